// Round 6
// baseline (450.254 us; speedup 1.0000x reference)
//
#include <hip/hip_runtime.h>
#include <hip/hip_bf16.h>
#include <math.h>

// Problem constants
#define BQ 8
#define C1N 512
#define N1 784          // 28*28
#define C2N 1024
#define M2 196          // 14*14
#define NROWS 6272      // 8*784
#define NROWSP 6400     // 25*256 (padded)
#define NTA 25          // A tiles of 256 rows
#define MEMN 20000
#define MEMNP 20224     // 79*256 (padded)
#define NTB 79          // B tiles of 256 rows
#define DIMK 1024
#define NKB 32          // K blocks of 32
#define KTE 8192        // elems per K-block per 256-row tile (4*256*8)
#define OUTHW 50176     // 224*224
#define NWG (NTA * NTB) // 1975

typedef unsigned short u16;
typedef __attribute__((ext_vector_type(8))) short short8v;
typedef __attribute__((ext_vector_type(4))) float f32x4;

// ---- order-preserving float <-> uint for atomicMin ----
static __device__ __forceinline__ unsigned int f2ord(float f) {
  unsigned int b = __float_as_uint(f);
  return (b & 0x80000000u) ? ~b : (b | 0x80000000u);
}
static __device__ __forceinline__ float ord2f(unsigned int u) {
  unsigned int b = (u & 0x80000000u) ? (u ^ 0x80000000u) : ~u;
  return __uint_as_float(b);
}

// ---- bf16 helpers (RNE) ----
static __device__ __forceinline__ u16 f2bf(float x) {
  unsigned u = __float_as_uint(x);
  u += 0x7FFFu + ((u >> 16) & 1u);
  return (u16)(u >> 16);
}
static __device__ __forceinline__ float bf2f(u16 b) {
  return __uint_as_float(((unsigned)b) << 16);
}

// ---- async global->LDS (16B per lane; LDS dest = uniform base + lane*16) ----
static __device__ __forceinline__ void gload16(const void* g, void* l) {
  __builtin_amdgcn_global_load_lds((const __attribute__((address_space(1))) void*)g,
                                   (__attribute__((address_space(3))) void*)l, 16, 0, 0);
}

// ---- tiled (k-major) element index, 256-row tiles ----
// layout: [tile][kb=32][c=4][row=256][e=8] ; element (grow=tile*256+row, k=kb*32+c*8+e)
static __device__ __forceinline__ size_t tiled_idx(int grow, int k) {
  int tile = grow >> 8, row = grow & 255;
  int kb = k >> 5, c = (k >> 3) & 3, e = k & 7;
  return (((size_t)(tile * NKB + kb) * 4 + c) * 256 + row) * 8 + e;
}

// ---- scrambled patchify flat-index decode ----
// Reference's patchify flattens per-batch in (kj, w, c, ki, h) row-major order:
//   L = (((kj*W + w)*C + c)*3 + ki)*H + h ; value = x[b, c, h+ki-1, w+kj-1] (0 if OOB)
static __device__ __forceinline__ float f1val(const float* __restrict__ x, int b, unsigned L) {
  unsigned h = L % 28u; unsigned t = L / 28u;
  unsigned ki = t % 3u; t /= 3u;
  unsigned c = t % 512u; t /= 512u;
  unsigned w = t % 28u; unsigned kj = t / 28u;
  unsigned y = h + ki - 1u;   // wraps to huge if -1
  unsigned xx = w + kj - 1u;
  if (y >= 28u || xx >= 28u) return 0.f;
  return x[(((size_t)b * 512u + c) * 28u + y) * 28u + xx];
}
static __device__ __forceinline__ float f2val(const float* __restrict__ x, int b, unsigned L) {
  unsigned h = L % 14u; unsigned t = L / 14u;
  unsigned ki = t % 3u; t /= 3u;
  unsigned c = t % 1024u; t /= 1024u;
  unsigned w = t % 14u; unsigned kj = t / 14u;
  unsigned y = h + ki - 1u;
  unsigned xx = w + kj - 1u;
  if (y >= 14u || xx >= 14u) return 0.f;
  return x[(((size_t)b * 1024u + c) * 14u + y) * 14u + xx];
}

// feats[b,n,j<512] = (sum_{u=0..8} F1[9*(512n+j)+u] + F1[...+4]) / 10  -> tiled layout
__global__ __launch_bounds__(256) void feat_a_bf(const float* __restrict__ feat1,
                                                 u16* __restrict__ At) {
  int id = blockIdx.x * 256 + threadIdx.x;
  if (id >= BQ * N1 * C1N) return;
  int j = id & 511; int t = id >> 9;
  int n = t % N1; int b = t / N1;
  unsigned L0 = 9u * (unsigned)(512 * n + j);
  float s = 0.f;
#pragma unroll
  for (int u = 0; u < 9; ++u) s += f1val(feat1, b, L0 + u);
  s += f1val(feat1, b, L0 + 4u);
  At[tiled_idx(b * N1 + n, j)] = f2bf(s * 0.1f);
}

// H2all[b][n2][i] = (1/18) sum_{u<18} F2[18*(512*n2+i)+u]
__global__ __launch_bounds__(256) void feat_b_stage1(const float* __restrict__ feat2,
                                                     float* __restrict__ H2all) {
  int b = blockIdx.x / M2;
  int n2 = blockIdx.x % M2;
  for (int i = threadIdx.x; i < 512; i += 256) {
    unsigned L0 = 18u * (unsigned)(512 * n2 + i);
    float s = 0.f;
#pragma unroll
    for (int u = 0; u < 18; ++u) s += f2val(feat2, b, L0 + u);
    H2all[((size_t)b * M2 + n2) * 512 + i] = s * (1.0f / 18.0f);
  }
}

// bilinear 14x14 -> 28x28 over the n2 grid, write feats[b,n,512+i] -> tiled layout
__global__ __launch_bounds__(256) void feat_b_stage2(const float* __restrict__ H2all,
                                                     u16* __restrict__ At) {
  int bn = blockIdx.x;
  int b = bn / N1, n = bn % N1;
  int y = n / 28, x = n % 28;
  float sy = 0.5f * (float)y - 0.25f;
  sy = fminf(fmaxf(sy, 0.f), 13.f);
  int y0 = (int)sy, y1 = min(y0 + 1, 13);
  float wy = sy - (float)y0;
  float sx = 0.5f * (float)x - 0.25f;
  sx = fminf(fmaxf(sx, 0.f), 13.f);
  int x0 = (int)sx, x1 = min(x0 + 1, 13);
  float wx = sx - (float)x0;
  float w00 = (1.f - wy) * (1.f - wx), w10 = wy * (1.f - wx);
  float w01 = (1.f - wy) * wx, w11 = wy * wx;
  const float* h00 = H2all + ((size_t)b * M2 + y0 * 14 + x0) * 512;
  const float* h10 = H2all + ((size_t)b * M2 + y1 * 14 + x0) * 512;
  const float* h01 = H2all + ((size_t)b * M2 + y0 * 14 + x1) * 512;
  const float* h11 = H2all + ((size_t)b * M2 + y1 * 14 + x1) * 512;
  for (int i = threadIdx.x; i < 512; i += 256) {
    float v = w00 * h00[i] + w10 * h10[i] + w01 * h01[i] + w11 * h11[i];
    At[tiled_idx(bn, 512 + i)] = f2bf(v);
  }
}

// memory fp32 -> bf16 tiled; rows [MEMN, MEMNP) = 0. One 8-elem unit per thread,
// dst linear in thread id -> coalesced writes.
__global__ __launch_bounds__(256) void memconv(const float* __restrict__ mem,
                                               u16* __restrict__ Bt) {
  int gid = blockIdx.x * 256 + threadIdx.x;
  if (gid >= NTB * NKB * 1024) return;
  int tile = gid >> 15;            // 32*1024 units per tile
  int within = gid & 32767;
  int kb = within >> 10;
  int u = within & 1023;
  int c = u >> 8, row = u & 255;
  int n = tile * 256 + row;
  int k0 = kb * 32 + c * 8;
  short8v o;
  if (n < MEMN) {
    const float* src = mem + (size_t)n * DIMK + k0;
    float4 a = *(const float4*)src;
    float4 b = *(const float4*)(src + 4);
    o[0] = (short)f2bf(a.x); o[1] = (short)f2bf(a.y);
    o[2] = (short)f2bf(a.z); o[3] = (short)f2bf(a.w);
    o[4] = (short)f2bf(b.x); o[5] = (short)f2bf(b.y);
    o[6] = (short)f2bf(b.z); o[7] = (short)f2bf(b.w);
  } else {
#pragma unroll
    for (int i = 0; i < 8; ++i) o[i] = 0;
  }
  *(short8v*)&Bt[(size_t)gid * 8] = o;
}

// fnorm from tiled bf16 feats: 1 wave per row
__global__ __launch_bounds__(256) void fnorm_bf(const u16* __restrict__ At,
                                                float* __restrict__ fnorm) {
  int row = blockIdx.x * 4 + (threadIdx.x >> 6);
  int lane = threadIdx.x & 63;
  float s = 0.f;
#pragma unroll
  for (int q = 0; q < 2; ++q) {
    int k = (lane + q * 64) * 8;
    short8v v = *(const short8v*)&At[tiled_idx(row, k)];
#pragma unroll
    for (int i = 0; i < 8; ++i) {
      float f = bf2f((u16)v[i]);
      s = fmaf(f, f, s);
    }
  }
#pragma unroll
  for (int off = 32; off; off >>= 1) s += __shfl_down(s, off, 64);
  if (lane == 0) fnorm[row] = s;
}

__global__ __launch_bounds__(256) void mnorm_kernel(const float* __restrict__ memory,
                                                    float* __restrict__ mnorm) {
  __shared__ float red[4];
  const int row = blockIdx.x;
  const float4 v = *(const float4*)&memory[(size_t)row * DIMK + threadIdx.x * 4];
  float s = v.x * v.x + v.y * v.y + v.z * v.z + v.w * v.w;
#pragma unroll
  for (int off = 32; off; off >>= 1) s += __shfl_down(s, off, 64);
  if ((threadIdx.x & 63) == 0) red[threadIdx.x >> 6] = s;
  __syncthreads();
  if (threadIdx.x == 0) mnorm[row] = red[0] + red[1] + red[2] + red[3];
}

// ---- bf16 MFMA distance GEMM + row-min ----
// 256x256 tile, BK=32, 8 waves (2Mx4N, per-wave 128x64), 3-buffer LDS pipeline,
// K-loop unrolled x3 (static slots), counted vmcnt, raw barriers, setprio cluster.
__global__ __launch_bounds__(512, 2) void dist_min_mfma(const u16* __restrict__ At,
                                                        const u16* __restrict__ Bt,
                                                        const float* __restrict__ mnorm,
                                                        unsigned int* __restrict__ minu) {
  __shared__ __align__(16) u16 As[3][8192];
  __shared__ __align__(16) u16 Bs[3][8192];
  const int t = threadIdx.x;
  const int wave = t >> 6, lane = t & 63;

  // bijective XCD chunking (m204): q=246, r=7
  int lid = blockIdx.x;
  const int q = NWG / 8, r = NWG % 8;
  int xcd = lid & 7, pos = lid >> 3;
  int wgid = (xcd < r ? xcd * (q + 1) : r * (q + 1) + (xcd - r) * q) + pos;
  // supertile: 5 row-tiles per group (25 = 5*5), rows fastest within a column
  int g = wgid / (NTB * 5), rem = wgid % (NTB * 5);
  int bx = rem / 5;            // col tile 0..78
  int by = g * 5 + rem % 5;    // row tile 0..24
  const int row0 = by * 256, col0 = bx * 256;

  f32x4 acc[8][4];
#pragma unroll
  for (int i = 0; i < 8; ++i)
#pragma unroll
    for (int j = 0; j < 4; ++j) acc[i][j] = (f32x4){0.f, 0.f, 0.f, 0.f};

  const int wr = (wave >> 2) * 128, wc = (wave & 3) * 64;
  const int frow = lane & 15, fc = lane >> 4;
  const int soff = wave * 512 + lane * 8;   // staging chunk offset (u16) within 8192-u16 tile

  const u16* aG = At + (size_t)by * (NKB * KTE) + soff;
  const u16* bG = Bt + (size_t)bx * (NKB * KTE) + soff;

  // stage one K-tile into static buffer slot; advance pointers by one K-tile
#define STAGE(buf)                                   \
  do {                                               \
    gload16(aG,        &As[buf][wave * 512]);        \
    gload16(aG + 4096, &As[buf][4096 + wave * 512]); \
    gload16(bG,        &Bs[buf][wave * 512]);        \
    gload16(bG + 4096, &Bs[buf][4096 + wave * 512]); \
    aG += KTE; bG += KTE;                            \
  } while (0)

  // compute one K-tile from static buffer slot
#define COMPUTE(buf)                                                                         \
  do {                                                                                       \
    short8v a[8], b[4];                                                                      \
    _Pragma("unroll") for (int mi = 0; mi < 8; ++mi)                                         \
        a[mi] = *(const short8v*)&As[buf][(fc * 256 + wr + mi * 16 + frow) * 8];             \
    _Pragma("unroll") for (int ni = 0; ni < 4; ++ni)                                         \
        b[ni] = *(const short8v*)&Bs[buf][(fc * 256 + wc + ni * 16 + frow) * 8];             \
    __builtin_amdgcn_s_setprio(1);                                                           \
    _Pragma("unroll") for (int mi = 0; mi < 8; ++mi)                                         \
      _Pragma("unroll") for (int ni = 0; ni < 4; ++ni)                                       \
          acc[mi][ni] = __builtin_amdgcn_mfma_f32_16x16x32_bf16(a[mi], b[ni], acc[mi][ni],   \
                                                                0, 0, 0);                    \
    __builtin_amdgcn_s_setprio(0);                                                           \
  } while (0)

#define WAITBAR(n)                                        \
  do {                                                    \
    asm volatile("s_waitcnt vmcnt(" #n ")" ::: "memory"); \
    __builtin_amdgcn_s_barrier();                         \
  } while (0)

  STAGE(0);
  STAGE(1);
  WAITBAR(4);   // tile 0 landed, tile 1 in flight

  // main: 10 iterations x 3 static slots = K-tiles 0..29 (prefetch through tile 31)
  for (int i = 0; i < 10; ++i) {
    STAGE(2); COMPUTE(0); WAITBAR(4);
    STAGE(0); COMPUTE(1); WAITBAR(4);
    STAGE(1); COMPUTE(2); WAITBAR(4);
  }
  // tail: K-tiles 30 (buf0), 31 (buf1)
  COMPUTE(0);
  WAITBAR(0);
  COMPUTE(1);
#undef STAGE
#undef COMPUTE
#undef WAITBAR

  // epilogue: v = mnorm[col] - 2*dot ; row-min across the 16-lane group
  float cmn[4];
#pragma unroll
  for (int ni = 0; ni < 4; ++ni) {
    int gn = col0 + wc + ni * 16 + frow;
    cmn[ni] = (gn < MEMN) ? mnorm[gn] : INFINITY;
  }
#pragma unroll
  for (int mi = 0; mi < 8; ++mi) {
#pragma unroll
    for (int rr = 0; rr < 4; ++rr) {
      float v = INFINITY;
#pragma unroll
      for (int ni = 0; ni < 4; ++ni)
        v = fminf(v, fmaf(-2.f, acc[mi][ni][rr], cmn[ni]));
#pragma unroll
      for (int off = 1; off < 16; off <<= 1)
        v = fminf(v, __shfl_xor(v, off, 64));
      if (frow == 0) {
        int grow = row0 + wr + mi * 16 + fc * 4 + rr;
        atomicMin(&minu[grow], f2ord(v));
      }
    }
  }
}

// ================= epilogue kernels =================

__global__ __launch_bounds__(256) void scores_kernel(const float* __restrict__ fnorm,
                                                     const unsigned int* __restrict__ minu,
                                                     float* __restrict__ scores) {
  int row = blockIdx.x * 256 + threadIdx.x;
  if (row >= NROWS) return;
  float d2 = fnorm[row] + ord2f(minu[row]);
  scores[row] = sqrtf(fmaxf(d2, 0.f));
}

__global__ __launch_bounds__(256) void image_max_kernel(const float* __restrict__ scores,
                                                        float* __restrict__ out) {
  __shared__ float red[4];
  const int b = blockIdx.x;
  float m = -INFINITY;
  for (int n = threadIdx.x; n < N1; n += 256) m = fmaxf(m, scores[b * N1 + n]);
#pragma unroll
  for (int off = 32; off; off >>= 1) m = fmaxf(m, __shfl_down(m, off, 64));
  if ((threadIdx.x & 63) == 0) red[threadIdx.x >> 6] = m;
  __syncthreads();
  if (threadIdx.x == 0) out[b] = fmaxf(fmaxf(red[0], red[1]), fmaxf(red[2], red[3]));
}

__global__ __launch_bounds__(256) void upsample_kernel(const float* __restrict__ scores,
                                                       float* __restrict__ out) {
  int o = blockIdx.x * 256 + threadIdx.x;
  if (o >= BQ * OUTHW) return;
  int b = o / OUTHW, rem = o % OUTHW;
  int oy = rem / 224, ox = rem % 224;
  float sy = ((float)oy + 0.5f) * 0.125f - 0.5f;
  sy = fminf(fmaxf(sy, 0.f), 27.f);
  int y0 = (int)sy, y1 = min(y0 + 1, 27);
  float wy = sy - (float)y0;
  float sx = ((float)ox + 0.5f) * 0.125f - 0.5f;
  sx = fminf(fmaxf(sx, 0.f), 27.f);
  int x0 = (int)sx, x1 = min(x0 + 1, 27);
  float wx = sx - (float)x0;
  const float* s = scores + b * N1;
  float v0 = s[y0 * 28 + x0] * (1.f - wy) + s[y1 * 28 + x0] * wy;
  float v1 = s[y0 * 28 + x1] * (1.f - wy) + s[y1 * 28 + x1] * wy;
  out[BQ + o] = v0 * (1.f - wx) + v1 * wx;
}

extern "C" void kernel_launch(void* const* d_in, const int* in_sizes, int n_in,
                              void* d_out, int out_size, void* d_ws, size_t ws_size,
                              hipStream_t stream) {
  const float* feat1 = (const float*)d_in[0];
  const float* feat2 = (const float*)d_in[1];
  const float* memory = (const float*)d_in[2];
  float* out = (float*)d_out;

  char* ws = (char*)d_ws;
  size_t off = 0;
  auto wsalloc = [&](size_t bytes) {
    void* p = ws + off;
    off += (bytes + 255) & ~(size_t)255;
    return p;
  };

  u16* At = (u16*)wsalloc((size_t)NTA * NKB * KTE * 2);
  u16* Bt = (u16*)wsalloc((size_t)NTB * NKB * KTE * 2);
  float* mnorm = (float*)wsalloc((size_t)MEMN * 4);
  float* fnorm = (float*)wsalloc((size_t)NROWS * 4);
  unsigned int* minu = (unsigned int*)wsalloc((size_t)NROWSP * 4);
  float* scores = (float*)wsalloc((size_t)NROWS * 4);
  // H2all aliases Bt: stream order guarantees feat_b_stage1/2 finish before memconv
  // overwrites Bt (8*196*512*4 = 3.2 MB << Bt's 41 MB).
  float* H2all = (float*)Bt;

  feat_a_bf<<<(BQ * N1 * C1N) / 256, 256, 0, stream>>>(feat1, At);
  feat_b_stage1<<<BQ * M2, 256, 0, stream>>>(feat2, H2all);
  feat_b_stage2<<<BQ * N1, 256, 0, stream>>>(H2all, At);
  memconv<<<(NTB * NKB * 1024) / 256, 256, 0, stream>>>(memory, Bt);
  fnorm_bf<<<NROWS / 4, 256, 0, stream>>>(At, fnorm);
  mnorm_kernel<<<MEMN, 256, 0, stream>>>(memory, mnorm);
  hipMemsetAsync(minu, 0xFF, (size_t)NROWSP * 4, stream);

  dist_min_mfma<<<NWG, 512, 0, stream>>>(At, Bt, mnorm, minu);

  scores_kernel<<<(NROWS + 255) / 256, 256, 0, stream>>>(fnorm, minu, scores);
  image_max_kernel<<<BQ, 256, 0, stream>>>(scores, out);
  upsample_kernel<<<(BQ * OUTHW + 255) / 256, 256, 0, stream>>>(scores, out);
}

// Round 7
// 406.999 us; speedup vs baseline: 1.1063x; 1.1063x over previous
//
#include <hip/hip_runtime.h>
#include <hip/hip_bf16.h>
#include <math.h>

// Problem constants
#define BQ 8
#define C1N 512
#define N1 784          // 28*28
#define C2N 1024
#define M2 196          // 14*14
#define NROWS 6272      // 8*784
#define NROWSP 6400     // 25*256 (padded)
#define NTA 25          // A tiles of 256 rows
#define MEMN 20000
#define MEMNP 20224     // 79*256 (padded)
#define NTB 79          // B tiles of 256 rows
#define DIMK 1024
#define NKB 16          // K blocks of 64
#define HLE 8192        // elems per half-tile (128 rows x 64 k)
#define OUTHW 50176     // 224*224
#define NWG (NTA * NTB) // 1975

typedef unsigned short u16;
typedef __attribute__((ext_vector_type(8))) short short8v;
typedef __attribute__((ext_vector_type(4))) float f32x4;

// ---- order-preserving float <-> uint for atomicMin ----
static __device__ __forceinline__ unsigned int f2ord(float f) {
  unsigned int b = __float_as_uint(f);
  return (b & 0x80000000u) ? ~b : (b | 0x80000000u);
}
static __device__ __forceinline__ float ord2f(unsigned int u) {
  unsigned int b = (u & 0x80000000u) ? (u ^ 0x80000000u) : ~u;
  return __uint_as_float(b);
}

// ---- bf16 helpers (RNE) ----
static __device__ __forceinline__ u16 f2bf(float x) {
  unsigned u = __float_as_uint(x);
  u += 0x7FFFu + ((u >> 16) & 1u);
  return (u16)(u >> 16);
}
static __device__ __forceinline__ float bf2f(u16 b) {
  return __uint_as_float(((unsigned)b) << 16);
}

// ---- async global->LDS (16B per lane; LDS dest = wave-uniform base + lane*16) ----
static __device__ __forceinline__ void gload16(const void* g, void* l) {
  __builtin_amdgcn_global_load_lds((const __attribute__((address_space(1))) void*)g,
                                   (__attribute__((address_space(3))) void*)l, 16, 0, 0);
}

// ---- tiled (k-major) element index, 256-row tiles, BK=64 halves ----
// layout: [tile][kb=16][half=2][c=8][row=128][e=8]
static __device__ __forceinline__ size_t tiled_idx(int grow, int k) {
  int tile = grow >> 8, rowt = grow & 255;
  int half = rowt >> 7, row = rowt & 127;
  int kb = k >> 6, c = (k >> 3) & 7, e = k & 7;
  return (((((size_t)tile * NKB + kb) * 2 + half) * 8 + c) * 128 + row) * 8 + e;
}

// ---- scrambled patchify flat-index decode ----
// Reference's patchify flattens per-batch in (kj, w, c, ki, h) row-major order:
//   L = (((kj*W + w)*C + c)*3 + ki)*H + h ; value = x[b, c, h+ki-1, w+kj-1] (0 if OOB)
static __device__ __forceinline__ float f1val(const float* __restrict__ x, int b, unsigned L) {
  unsigned h = L % 28u; unsigned t = L / 28u;
  unsigned ki = t % 3u; t /= 3u;
  unsigned c = t % 512u; t /= 512u;
  unsigned w = t % 28u; unsigned kj = t / 28u;
  unsigned y = h + ki - 1u;   // wraps to huge if -1
  unsigned xx = w + kj - 1u;
  if (y >= 28u || xx >= 28u) return 0.f;
  return x[(((size_t)b * 512u + c) * 28u + y) * 28u + xx];
}
static __device__ __forceinline__ float f2val(const float* __restrict__ x, int b, unsigned L) {
  unsigned h = L % 14u; unsigned t = L / 14u;
  unsigned ki = t % 3u; t /= 3u;
  unsigned c = t % 1024u; t /= 1024u;
  unsigned w = t % 14u; unsigned kj = t / 14u;
  unsigned y = h + ki - 1u;
  unsigned xx = w + kj - 1u;
  if (y >= 14u || xx >= 14u) return 0.f;
  return x[(((size_t)b * 1024u + c) * 14u + y) * 14u + xx];
}

// feats[b,n,j<512] = (sum_{u=0..8} F1[9*(512n+j)+u] + F1[...+4]) / 10  -> tiled layout
__global__ __launch_bounds__(256) void feat_a_bf(const float* __restrict__ feat1,
                                                 u16* __restrict__ At) {
  int id = blockIdx.x * 256 + threadIdx.x;
  if (id >= BQ * N1 * C1N) return;
  int j = id & 511; int t = id >> 9;
  int n = t % N1; int b = t / N1;
  unsigned L0 = 9u * (unsigned)(512 * n + j);
  float s = 0.f;
#pragma unroll
  for (int u = 0; u < 9; ++u) s += f1val(feat1, b, L0 + u);
  s += f1val(feat1, b, L0 + 4u);
  At[tiled_idx(b * N1 + n, j)] = f2bf(s * 0.1f);
}

// H2all[b][n2][i] = (1/18) sum_{u<18} F2[18*(512*n2+i)+u]
__global__ __launch_bounds__(256) void feat_b_stage1(const float* __restrict__ feat2,
                                                     float* __restrict__ H2all) {
  int b = blockIdx.x / M2;
  int n2 = blockIdx.x % M2;
  for (int i = threadIdx.x; i < 512; i += 256) {
    unsigned L0 = 18u * (unsigned)(512 * n2 + i);
    float s = 0.f;
#pragma unroll
    for (int u = 0; u < 18; ++u) s += f2val(feat2, b, L0 + u);
    H2all[((size_t)b * M2 + n2) * 512 + i] = s * (1.0f / 18.0f);
  }
}

// bilinear 14x14 -> 28x28 over the n2 grid, write feats[b,n,512+i] -> tiled layout
__global__ __launch_bounds__(256) void feat_b_stage2(const float* __restrict__ H2all,
                                                     u16* __restrict__ At) {
  int bn = blockIdx.x;
  int b = bn / N1, n = bn % N1;
  int y = n / 28, x = n % 28;
  float sy = 0.5f * (float)y - 0.25f;
  sy = fminf(fmaxf(sy, 0.f), 13.f);
  int y0 = (int)sy, y1 = min(y0 + 1, 13);
  float wy = sy - (float)y0;
  float sx = 0.5f * (float)x - 0.25f;
  sx = fminf(fmaxf(sx, 0.f), 13.f);
  int x0 = (int)sx, x1 = min(x0 + 1, 13);
  float wx = sx - (float)x0;
  float w00 = (1.f - wy) * (1.f - wx), w10 = wy * (1.f - wx);
  float w01 = (1.f - wy) * wx, w11 = wy * wx;
  const float* h00 = H2all + ((size_t)b * M2 + y0 * 14 + x0) * 512;
  const float* h10 = H2all + ((size_t)b * M2 + y1 * 14 + x0) * 512;
  const float* h01 = H2all + ((size_t)b * M2 + y0 * 14 + x1) * 512;
  const float* h11 = H2all + ((size_t)b * M2 + y1 * 14 + x1) * 512;
  for (int i = threadIdx.x; i < 512; i += 256) {
    float v = w00 * h00[i] + w10 * h10[i] + w01 * h01[i] + w11 * h11[i];
    At[tiled_idx(bn, 512 + i)] = f2bf(v);
  }
}

// memory fp32 -> bf16 tiled; rows [MEMN, MEMNP) = 0. One 8-elem unit per thread,
// dst linear in thread id -> coalesced writes.
__global__ __launch_bounds__(256) void memconv(const float* __restrict__ mem,
                                               u16* __restrict__ Bt) {
  int gid = blockIdx.x * 256 + threadIdx.x;
  if (gid >= NTB * 32768) return;
  int tile = gid >> 15;            // 32768 8-elem units per tile
  int w = gid & 32767;
  int kb = w >> 11;
  int half = (w >> 10) & 1;
  int c = (w >> 7) & 7;
  int row = w & 127;
  int n = tile * 256 + half * 128 + row;
  int k0 = kb * 64 + c * 8;
  short8v o;
  if (n < MEMN) {
    const float* src = mem + (size_t)n * DIMK + k0;
    float4 a = *(const float4*)src;
    float4 b = *(const float4*)(src + 4);
    o[0] = (short)f2bf(a.x); o[1] = (short)f2bf(a.y);
    o[2] = (short)f2bf(a.z); o[3] = (short)f2bf(a.w);
    o[4] = (short)f2bf(b.x); o[5] = (short)f2bf(b.y);
    o[6] = (short)f2bf(b.z); o[7] = (short)f2bf(b.w);
  } else {
#pragma unroll
    for (int i = 0; i < 8; ++i) o[i] = 0;
  }
  *(short8v*)&Bt[(size_t)gid * 8] = o;
}

// fnorm from tiled bf16 feats: 1 wave per row
__global__ __launch_bounds__(256) void fnorm_bf(const u16* __restrict__ At,
                                                float* __restrict__ fnorm) {
  int row = blockIdx.x * 4 + (threadIdx.x >> 6);
  int lane = threadIdx.x & 63;
  float s = 0.f;
#pragma unroll
  for (int q = 0; q < 2; ++q) {
    int k = (lane + q * 64) * 8;
    short8v v = *(const short8v*)&At[tiled_idx(row, k)];
#pragma unroll
    for (int i = 0; i < 8; ++i) {
      float f = bf2f((u16)v[i]);
      s = fmaf(f, f, s);
    }
  }
#pragma unroll
  for (int off = 32; off; off >>= 1) s += __shfl_down(s, off, 64);
  if (lane == 0) fnorm[row] = s;
}

__global__ __launch_bounds__(256) void mnorm_kernel(const float* __restrict__ memory,
                                                    float* __restrict__ mnorm) {
  __shared__ float red[4];
  const int row = blockIdx.x;
  const float4 v = *(const float4*)&memory[(size_t)row * DIMK + threadIdx.x * 4];
  float s = v.x * v.x + v.y * v.y + v.z * v.z + v.w * v.w;
#pragma unroll
  for (int off = 32; off; off >>= 1) s += __shfl_down(s, off, 64);
  if ((threadIdx.x & 63) == 0) red[threadIdx.x >> 6] = s;
  __syncthreads();
  if (threadIdx.x == 0) mnorm[row] = red[0] + red[1] + red[2] + red[3];
}

// ---- bf16 MFMA distance GEMM + row-min ----
// 256x256 tile, BK=64, 8 waves (2Mx4N, per-wave 128x64), 2 LDS slots (128 KB),
// 4 phases per K-tile: {ds_read quadrant frags || stage half-tiles} -> barrier ->
// setprio+16 MFMA -> barrier. Counted landing slack: tile T+1 staged in T's
// phases 0-1, consumed from phase 0 of T+1 (vmcnt after Q3's MFMAs).
__global__ __launch_bounds__(512, 1) void dist_min_mfma(const u16* __restrict__ At,
                                                        const u16* __restrict__ Bt,
                                                        const float* __restrict__ mnorm,
                                                        unsigned int* __restrict__ minu) {
  __shared__ __align__(16) u16 LDS[2][2][2][HLE];   // [slot][A/B][half][128x64]
  const int t = threadIdx.x;
  const int wave = t >> 6, lane = t & 63;

  // bijective XCD chunking (m204): q=246, r=7
  int lid = blockIdx.x;
  const int q = NWG / 8, r = NWG % 8;
  int xcd = lid & 7, pos = lid >> 3;
  int wgid = (xcd < r ? xcd * (q + 1) : r * (q + 1) + (xcd - r) * q) + pos;
  // supertile: 5 row-tiles per group (25 = 5*5), rows fastest within a column
  int g = wgid / (NTB * 5), rem = wgid % (NTB * 5);
  int bx = rem / 5;            // col tile 0..78
  int by = g * 5 + rem % 5;    // row tile 0..24
  const int row0 = by * 256, col0 = bx * 256;

  f32x4 acc[8][4];
#pragma unroll
  for (int i = 0; i < 8; ++i)
#pragma unroll
    for (int j = 0; j < 4; ++j) acc[i][j] = (f32x4){0.f, 0.f, 0.f, 0.f};

  const int wr = (wave >> 2) * 128, wc = (wave & 3) * 64;
  const int frow = lane & 15, fc = lane >> 4;
  const int ha = wave >> 2;          // A half this wave reads
  const int hb = (wave & 3) >> 1;    // B half this wave reads
  const int aoff = (fc * 128 + frow) * 8;
  const int boff = (fc * 128 + (wave & 1) * 64 + frow) * 8;
  const int so = wave * 512 + lane * 8;   // staging src offset within a half

  const u16* aGb = At + (size_t)by * (NKB * 2 * HLE);
  const u16* bGb = Bt + (size_t)bx * (NKB * 2 * HLE);

  // stage half h of matrix mat, K-tile kb, into LDS slot
#define STAGE_HALF(mat, slot, h, kb)                                              \
  do {                                                                            \
    const u16* s_ = ((mat) ? bGb : aGb) + ((size_t)(kb) * 2 + (h)) * HLE + so;    \
    gload16(s_,        &LDS[slot][mat][h][wave * 512]);                           \
    gload16(s_ + 4096, &LDS[slot][mat][h][4096 + wave * 512]);                    \
  } while (0)

#define SPRIO1 __builtin_amdgcn_s_setprio(1)
#define SPRIO0 __builtin_amdgcn_s_setprio(0)
#define SBAR __builtin_amdgcn_s_barrier()

  // one K-tile: slot S (compile-time), optionally staging K-tile kbn into S^1
#define TILE_STEP(S, STG, kbn)                                                               \
  do {                                                                                       \
    short8v a03[4][2], a47[4][2], b01[2][2], b23[2][2];                                      \
    /* Phase 0 (Q0: mi0-3 x ni0-1) */                                                        \
    _Pragma("unroll") for (int mi = 0; mi < 4; ++mi)                                         \
      _Pragma("unroll") for (int kk = 0; kk < 2; ++kk)                                       \
        a03[mi][kk] = *(const short8v*)&LDS[S][0][ha][kk * 4096 + mi * 128 + aoff];          \
    _Pragma("unroll") for (int ni = 0; ni < 2; ++ni)                                         \
      _Pragma("unroll") for (int kk = 0; kk < 2; ++kk)                                       \
        b01[ni][kk] = *(const short8v*)&LDS[S][1][hb][kk * 4096 + ni * 128 + boff];          \
    if (STG) { STAGE_HALF(0, (S) ^ 1, 0, kbn); STAGE_HALF(0, (S) ^ 1, 1, kbn); }             \
    SBAR;                                                                                    \
    SPRIO1;                                                                                  \
    _Pragma("unroll") for (int mi = 0; mi < 4; ++mi)                                         \
      _Pragma("unroll") for (int ni = 0; ni < 2; ++ni)                                       \
        _Pragma("unroll") for (int kk = 0; kk < 2; ++kk)                                     \
          acc[mi][ni] = __builtin_amdgcn_mfma_f32_16x16x32_bf16(a03[mi][kk], b01[ni][kk],    \
                                                                acc[mi][ni], 0, 0, 0);       \
    SPRIO0;                                                                                  \
    SBAR;                                                                                    \
    /* Phase 1 (Q1: mi0-3 x ni2-3) */                                                        \
    _Pragma("unroll") for (int ni = 0; ni < 2; ++ni)                                         \
      _Pragma("unroll") for (int kk = 0; kk < 2; ++kk)                                       \
        b23[ni][kk] = *(const short8v*)&LDS[S][1][hb][kk * 4096 + (ni + 2) * 128 + boff];    \
    if (STG) { STAGE_HALF(1, (S) ^ 1, 0, kbn); STAGE_HALF(1, (S) ^ 1, 1, kbn); }             \
    SBAR;                                                                                    \
    SPRIO1;                                                                                  \
    _Pragma("unroll") for (int mi = 0; mi < 4; ++mi)                                         \
      _Pragma("unroll") for (int ni = 0; ni < 2; ++ni)                                       \
        _Pragma("unroll") for (int kk = 0; kk < 2; ++kk)                                     \
          acc[mi][ni + 2] = __builtin_amdgcn_mfma_f32_16x16x32_bf16(a03[mi][kk],             \
                                b23[ni][kk], acc[mi][ni + 2], 0, 0, 0);                      \
    SPRIO0;                                                                                  \
    SBAR;                                                                                    \
    /* Phase 2 (Q2: mi4-7 x ni2-3) */                                                        \
    _Pragma("unroll") for (int mi = 0; mi < 4; ++mi)                                         \
      _Pragma("unroll") for (int kk = 0; kk < 2; ++kk)                                       \
        a47[mi][kk] = *(const short8v*)&LDS[S][0][ha][kk * 4096 + (mi + 4) * 128 + aoff];    \
    SBAR;                                                                                    \
    SPRIO1;                                                                                  \
    _Pragma("unroll") for (int mi = 0; mi < 4; ++mi)                                         \
      _Pragma("unroll") for (int ni = 0; ni < 2; ++ni)                                       \
        _Pragma("unroll") for (int kk = 0; kk < 2; ++kk)                                     \
          acc[mi + 4][ni + 2] = __builtin_amdgcn_mfma_f32_16x16x32_bf16(a47[mi][kk],         \
                                    b23[ni][kk], acc[mi + 4][ni + 2], 0, 0, 0);              \
    SPRIO0;                                                                                  \
    SBAR;                                                                                    \
    /* Phase 3 (Q3: mi4-7 x ni0-1), then tile-boundary landing wait */                       \
    SPRIO1;                                                                                  \
    _Pragma("unroll") for (int mi = 0; mi < 4; ++mi)                                         \
      _Pragma("unroll") for (int ni = 0; ni < 2; ++ni)                                       \
        _Pragma("unroll") for (int kk = 0; kk < 2; ++kk)                                     \
          acc[mi + 4][ni] = __builtin_amdgcn_mfma_f32_16x16x32_bf16(a47[mi][kk],             \
                                b01[ni][kk], acc[mi + 4][ni], 0, 0, 0);                      \
    SPRIO0;                                                                                  \
    if (STG) asm volatile("s_waitcnt vmcnt(0)" ::: "memory");                                \
    SBAR;                                                                                    \
  } while (0)

  // prologue: stage K-tile 0 into slot 0
  STAGE_HALF(0, 0, 0, 0);
  STAGE_HALF(0, 0, 1, 0);
  STAGE_HALF(1, 0, 0, 0);
  STAGE_HALF(1, 0, 1, 0);
  asm volatile("s_waitcnt vmcnt(0)" ::: "memory");
  SBAR;

  // K-tiles 0..13 in pairs; tile T computed from slot T&1, stages tile T+1
#pragma unroll 1
  for (int i = 0; i < 7; ++i) {
    TILE_STEP(0, true, 2 * i + 1);
    TILE_STEP(1, true, 2 * i + 2);
  }
  TILE_STEP(0, true, 15);   // tile 14, stages tile 15
  TILE_STEP(1, false, 0);   // tile 15, no staging
#undef TILE_STEP
#undef STAGE_HALF

  // epilogue: v = mnorm[col] - 2*dot ; row-min across the 16-lane group
  float cmn[4];
#pragma unroll
  for (int ni = 0; ni < 4; ++ni) {
    int gn = col0 + wc + ni * 16 + frow;
    cmn[ni] = (gn < MEMN) ? mnorm[gn] : INFINITY;
  }
#pragma unroll
  for (int mi = 0; mi < 8; ++mi) {
#pragma unroll
    for (int rr = 0; rr < 4; ++rr) {
      float v = INFINITY;
#pragma unroll
      for (int ni = 0; ni < 4; ++ni)
        v = fminf(v, fmaf(-2.f, acc[mi][ni][rr], cmn[ni]));
#pragma unroll
      for (int off = 1; off < 16; off <<= 1)
        v = fminf(v, __shfl_xor(v, off, 64));
      if (frow == 0) {
        int grow = row0 + wr + mi * 16 + fc * 4 + rr;
        atomicMin(&minu[grow], f2ord(v));
      }
    }
  }
}

// ================= epilogue kernels =================

__global__ __launch_bounds__(256) void scores_kernel(const float* __restrict__ fnorm,
                                                     const unsigned int* __restrict__ minu,
                                                     float* __restrict__ scores) {
  int row = blockIdx.x * 256 + threadIdx.x;
  if (row >= NROWS) return;
  float d2 = fnorm[row] + ord2f(minu[row]);
  scores[row] = sqrtf(fmaxf(d2, 0.f));
}

__global__ __launch_bounds__(256) void image_max_kernel(const float* __restrict__ scores,
                                                        float* __restrict__ out) {
  __shared__ float red[4];
  const int b = blockIdx.x;
  float m = -INFINITY;
  for (int n = threadIdx.x; n < N1; n += 256) m = fmaxf(m, scores[b * N1 + n]);
#pragma unroll
  for (int off = 32; off; off >>= 1) m = fmaxf(m, __shfl_down(m, off, 64));
  if ((threadIdx.x & 63) == 0) red[threadIdx.x >> 6] = m;
  __syncthreads();
  if (threadIdx.x == 0) out[b] = fmaxf(fmaxf(red[0], red[1]), fmaxf(red[2], red[3]));
}

__global__ __launch_bounds__(256) void upsample_kernel(const float* __restrict__ scores,
                                                       float* __restrict__ out) {
  int o = blockIdx.x * 256 + threadIdx.x;
  if (o >= BQ * OUTHW) return;
  int b = o / OUTHW, rem = o % OUTHW;
  int oy = rem / 224, ox = rem % 224;
  float sy = ((float)oy + 0.5f) * 0.125f - 0.5f;
  sy = fminf(fmaxf(sy, 0.f), 27.f);
  int y0 = (int)sy, y1 = min(y0 + 1, 27);
  float wy = sy - (float)y0;
  float sx = ((float)ox + 0.5f) * 0.125f - 0.5f;
  sx = fminf(fmaxf(sx, 0.f), 27.f);
  int x0 = (int)sx, x1 = min(x0 + 1, 27);
  float wx = sx - (float)x0;
  const float* s = scores + b * N1;
  float v0 = s[y0 * 28 + x0] * (1.f - wy) + s[y1 * 28 + x0] * wy;
  float v1 = s[y0 * 28 + x1] * (1.f - wy) + s[y1 * 28 + x1] * wy;
  out[BQ + o] = v0 * (1.f - wx) + v1 * wx;
}

extern "C" void kernel_launch(void* const* d_in, const int* in_sizes, int n_in,
                              void* d_out, int out_size, void* d_ws, size_t ws_size,
                              hipStream_t stream) {
  const float* feat1 = (const float*)d_in[0];
  const float* feat2 = (const float*)d_in[1];
  const float* memory = (const float*)d_in[2];
  float* out = (float*)d_out;

  char* ws = (char*)d_ws;
  size_t off = 0;
  auto wsalloc = [&](size_t bytes) {
    void* p = ws + off;
    off += (bytes + 255) & ~(size_t)255;
    return p;
  };

  u16* At = (u16*)wsalloc((size_t)NTA * NKB * 2 * HLE * 2);
  u16* Bt = (u16*)wsalloc((size_t)NTB * NKB * 2 * HLE * 2);
  float* mnorm = (float*)wsalloc((size_t)MEMN * 4);
  float* fnorm = (float*)wsalloc((size_t)NROWS * 4);
  unsigned int* minu = (unsigned int*)wsalloc((size_t)NROWSP * 4);
  float* scores = (float*)wsalloc((size_t)NROWS * 4);
  // H2all aliases Bt: stream order guarantees feat_b_stage1/2 finish before memconv
  // overwrites Bt (8*196*512*4 = 3.2 MB << Bt's 41 MB).
  float* H2all = (float*)Bt;

  feat_a_bf<<<(BQ * N1 * C1N) / 256, 256, 0, stream>>>(feat1, At);
  feat_b_stage1<<<BQ * M2, 256, 0, stream>>>(feat2, H2all);
  feat_b_stage2<<<BQ * N1, 256, 0, stream>>>(H2all, At);
  memconv<<<(NTB * 32768) / 256, 256, 0, stream>>>(memory, Bt);
  fnorm_bf<<<NROWS / 4, 256, 0, stream>>>(At, fnorm);
  mnorm_kernel<<<MEMN, 256, 0, stream>>>(memory, mnorm);
  hipMemsetAsync(minu, 0xFF, (size_t)NROWSP * 4, stream);

  dist_min_mfma<<<NWG, 512, 0, stream>>>(At, Bt, mnorm, minu);

  scores_kernel<<<(NROWS + 255) / 256, 256, 0, stream>>>(fnorm, minu, scores);
  image_max_kernel<<<BQ, 256, 0, stream>>>(scores, out);
  upsample_kernel<<<(BQ * OUTHW + 255) / 256, 256, 0, stream>>>(scores, out);
}